// Round 10
// baseline (335.515 us; speedup 1.0000x reference)
//
#include <hip/hip_runtime.h>

// ---------------- problem constants ----------------
#define N0 262144
#define N1 32768
#define N2 4096
#define EPSBN 1e-5f

typedef unsigned short ush_t;
typedef __bf16 bf16x8 __attribute__((ext_vector_type(8)));
typedef float  f32x4  __attribute__((ext_vector_type(4)));

union ufcast { unsigned int u; float f; };
__device__ __forceinline__ float bflo(unsigned int p) { ufcast x; x.u = p << 16;          return x.f; }
__device__ __forceinline__ float bfhi(unsigned int p) { ufcast x; x.u = p & 0xffff0000u; return x.f; }
__device__ __forceinline__ ush_t f2bf(float f) {
    ufcast x; x.f = f;
    unsigned int u = x.u + 0x7fffu + ((x.u >> 16) & 1u);
    return (ush_t)(u >> 16);
}
__device__ __forceinline__ bf16x8 as_bf8(uint4 u) {
    union { uint4 u; bf16x8 b; } x; x.u = u; return x.b;
}

// ---------------- weight prep: W[K][CIN][COUT] f32 -> Wb[chunk][COUTP][32] bf16 ----------------
template<int K, int CIN, int CINP_W, int COUT, int COUTP, int NCH>
__device__ __forceinline__ void prep_stage(const float* __restrict__ W, ush_t* __restrict__ Wb, int e) {
    const int k  = e & 31;
    const int n  = (e >> 5) % COUTP;
    const int ch = e / (32 * COUTP);
    const int kp = ch * 32 + k;
    const int t  = kp / CINP_W;
    const int c  = kp % CINP_W;
    float v = 0.f;
    if (t < K && c < CIN && n < COUT) v = W[((size_t)t * CIN + c) * COUT + n];
    Wb[e] = f2bf(v);
}

__global__ __launch_bounds__(256) void prep_weights(
    const float* w0, const float* wd0, const float* w1, const float* wd1, const float* wp,
    ush_t* wbA, ush_t* wbB, ush_t* wbC, ush_t* wbD, ush_t* wbE)
{
    const int e = blockIdx.x * 256 + threadIdx.x;
    switch (blockIdx.y) {
        case 0: if (e <   4096) prep_stage<27,  3,  4, 24, 32,  4>(w0,  wbA, e); break;
        case 1: if (e <  12288) prep_stage< 8, 24, 32, 48, 48,  8>(wd0, wbB, e); break;
        case 2: if (e <  82944) prep_stage<27, 48, 64, 48, 48, 54>(w1,  wbC, e); break;
        case 3: if (e <  49152) prep_stage< 8, 48, 64, 96, 96, 16>(wd1, wbD, e); break;
        case 4: if (e < 248832) prep_stage<27, 96, 96, 96, 96, 81>(wp,  wbE, e); break;
    }
}

// ---------------- input prep: data [N0,3] f32 -> XA [N0,4] bf16 ----------------
__global__ void prep_input(const float* __restrict__ data, ush_t* __restrict__ xa, int n)
{
    int m = blockIdx.x * blockDim.x + threadIdx.x;
    if (m >= n) return;
    const float* dp = data + (size_t)3 * m;
    unsigned int h0 = f2bf(dp[0]), h1 = f2bf(dp[1]), h2 = f2bf(dp[2]);
    uint2 v; v.x = h0 | (h1 << 16); v.y = h2;
    ((uint2*)xa)[m] = v;
}

// ---------------- stage A: MFMA conv, 128 rows/block, 2 frags/wave, coalesced bf16 store ----------------
__global__ __launch_bounds__(256) void mconvA(
    const ush_t* __restrict__ xa,     // [N0,4] bf16
    const int*   __restrict__ neigh,  // [N0,27]
    const ush_t* __restrict__ Wb,     // [4][32][32] bf16
    ush_t*       __restrict__ y)      // [N0,24] bf16 (pre-BN)
{
    __shared__ int   nl[128][28];
    __shared__ ush_t ys[128 * 24];
    const int tid = threadIdx.x;
    const int block0 = blockIdx.x * 128;

    for (int i = tid; i < 128 * 27; i += 256)
        nl[i / 27][i % 27] = neigh[(size_t)block0 * 27 + i];
    __syncthreads();

    const int lane = tid & 63, wave = tid >> 6;
    const int quad = lane >> 4, l15 = lane & 15;

    f32x4 acc[2][2] = {};
#pragma unroll
    for (int ch = 0; ch < 4; ++ch) {
        const int tA = ch * 8 + quad * 2;
        uint4 au[2];
#pragma unroll
        for (int g = 0; g < 2; ++g) {
            const int lr = wave * 32 + g * 16 + l15;
            uint4 v = make_uint4(0, 0, 0, 0);
            if (ch < 3) {
                const uint2 lo = ((const uint2*)xa)[nl[lr][tA]];
                const uint2 hi = ((const uint2*)xa)[nl[lr][tA + 1]];
                v = make_uint4(lo.x, lo.y, hi.x, hi.y);
            } else {
                if (quad == 0) {
                    const uint2 lo = ((const uint2*)xa)[nl[lr][24]];
                    const uint2 hi = ((const uint2*)xa)[nl[lr][25]];
                    v = make_uint4(lo.x, lo.y, hi.x, hi.y);
                } else if (quad == 1) {
                    const uint2 lo = ((const uint2*)xa)[nl[lr][26]];
                    v = make_uint4(lo.x, lo.y, 0, 0);
                }
            }
            au[g] = v;
        }
#pragma unroll
        for (int ct = 0; ct < 2; ++ct) {
            const int n = ct * 16 + l15;
            const uint4 bu = *(const uint4*)(Wb + ((size_t)ch * 32 + n) * 32 + quad * 8);
            const bf16x8 bf = as_bf8(bu);
            acc[0][ct] = __builtin_amdgcn_mfma_f32_16x16x32_bf16(as_bf8(au[0]), bf, acc[0][ct], 0, 0, 0);
            acc[1][ct] = __builtin_amdgcn_mfma_f32_16x16x32_bf16(as_bf8(au[1]), bf, acc[1][ct], 0, 0, 0);
        }
    }

    // repack to LDS, then coalesced global store
#pragma unroll
    for (int g = 0; g < 2; ++g)
#pragma unroll
        for (int ct = 0; ct < 2; ++ct) {
            const int col = ct * 16 + l15;
            if (col < 24) {
#pragma unroll
                for (int r = 0; r < 4; ++r) {
                    const int lr = wave * 32 + g * 16 + quad * 4 + r;
                    ys[lr * 24 + col] = f2bf(acc[g][ct][r]);
                }
            }
        }
    __syncthreads();
    {
        const ush_t* src = ys + tid * 12;
        ush_t* dst = y + (size_t)block0 * 24 + tid * 12;
        *(uint2*)(dst)     = *(const uint2*)(src);
        *(uint2*)(dst + 4) = *(const uint2*)(src + 4);
        *(uint2*)(dst + 8) = *(const uint2*)(src + 8);
    }
}

// ---------------- statsA: bf16 y0 [N0,24] -> ss0 (small grid, binned atomics) ----------------
__global__ __launch_bounds__(256) void statsA(
    const ush_t* __restrict__ y0,
    const float* __restrict__ gamma_, const float* __restrict__ beta_,
    float* __restrict__ bins, int* __restrict__ counter, float* __restrict__ ss_out)
{
    __shared__ float lsq[48];
    __shared__ int lastflag;
    const int tid = threadIdx.x;
    if (tid < 48) lsq[tid] = 0.f;
    __syncthreads();

    const int total8 = N0 * 24 / 8;
    int i = blockIdx.x * 256 + tid;
    const int stride = gridDim.x * 256;
    const int c0 = (i * 8) % 24;

    float s[8] = {0,0,0,0,0,0,0,0}, q[8] = {0,0,0,0,0,0,0,0};
    for (; i < total8; i += stride) {
        const uint4 v = ((const uint4*)y0)[i];
        const unsigned int w4[4] = {v.x, v.y, v.z, v.w};
#pragma unroll
        for (int h = 0; h < 4; ++h) {
            const float a = bflo(w4[h]), b2 = bfhi(w4[h]);
            s[2*h] += a;  q[2*h] += a * a;
            s[2*h+1] += b2; q[2*h+1] += b2 * b2;
        }
    }
#pragma unroll
    for (int j = 0; j < 8; ++j) {
        atomicAdd(&lsq[c0 + j], s[j]);
        atomicAdd(&lsq[24 + c0 + j], q[j]);
    }
    __syncthreads();
    if (tid < 48) atomicAdd(&bins[(blockIdx.x & 15) * 48 + tid], lsq[tid]);
    if (tid == 0) {
        __threadfence();
        int p = __hip_atomic_fetch_add(counter, 1, __ATOMIC_ACQ_REL, __HIP_MEMORY_SCOPE_AGENT);
        lastflag = (p == (int)gridDim.x - 1) ? 1 : 0;
    }
    __syncthreads();
    if (lastflag && tid < 24) {
        float S = 0.f, Q = 0.f;
        for (int b2 = 0; b2 < 16; ++b2) {
            S += __hip_atomic_load(&bins[b2 * 48 + tid],      __ATOMIC_RELAXED, __HIP_MEMORY_SCOPE_AGENT);
            Q += __hip_atomic_load(&bins[b2 * 48 + 24 + tid], __ATOMIC_RELAXED, __HIP_MEMORY_SCOPE_AGENT);
        }
        const float mu  = S / (float)N0;
        const float var = fmaxf(Q / (float)N0 - mu * mu, 0.f);
        const float scale = gamma_[tid] / sqrtf(var + EPSBN);
        ss_out[tid]      = scale;
        ss_out[24 + tid] = beta_[tid] - mu * scale;
    }
}

// ---------------- stage B: gather y0 bf16 + fused BN/ReLU -> MFMA ----------------
__global__ __launch_bounds__(256) void mconvB(
    const ush_t* __restrict__ y0,     // [N0,24] bf16 pre-BN
    const float* __restrict__ ss,     // [48]
    const int*   __restrict__ child,  // [N1,8]
    const ush_t* __restrict__ Wb,     // [8][48][32]
    float*       __restrict__ yout, size_t ystride)
{
    const int tid = threadIdx.x;
    const int lane = tid & 63, wave = tid >> 6;
    const int quad = lane >> 4, l15 = lane & 15;
    const int kg = blockIdx.y;
    const int rowA = blockIdx.x * 64 + wave * 16 + l15;
    const int c0 = quad * 8;

    float sc[8], sh[8];
    if (c0 < 24) {
#pragma unroll
        for (int j = 0; j < 8; ++j) { sc[j] = ss[c0 + j]; sh[j] = ss[24 + c0 + j]; }
    }

    f32x4 acc[3] = {};
#pragma unroll
    for (int ci = 0; ci < 4; ++ci) {
        const int t = kg * 4 + ci;
        const int idx = child[(size_t)rowA * 8 + t];
        uint4 au = make_uint4(0, 0, 0, 0);
        if (c0 < 24) {
            const uint4 raw = *(const uint4*)(y0 + (size_t)idx * 24 + c0);
            const unsigned int w4[4] = {raw.x, raw.y, raw.z, raw.w};
            unsigned int o4[4];
#pragma unroll
            for (int h = 0; h < 4; ++h) {
                const float a0 = fmaxf(bflo(w4[h]) * sc[2 * h]     + sh[2 * h],     0.f);
                const float a1 = fmaxf(bfhi(w4[h]) * sc[2 * h + 1] + sh[2 * h + 1], 0.f);
                o4[h] = (unsigned)f2bf(a0) | ((unsigned)f2bf(a1) << 16);
            }
            au = make_uint4(o4[0], o4[1], o4[2], o4[3]);
        }
        const bf16x8 af = as_bf8(au);
#pragma unroll
        for (int ct = 0; ct < 3; ++ct) {
            const int n = ct * 16 + l15;
            const uint4 bu = *(const uint4*)(Wb + ((size_t)(kg * 4 + ci) * 48 + n) * 32 + quad * 8);
            acc[ct] = __builtin_amdgcn_mfma_f32_16x16x32_bf16(af, as_bf8(bu), acc[ct], 0, 0, 0);
        }
    }

    float* yo = yout + (size_t)kg * ystride;
#pragma unroll
    for (int ct = 0; ct < 3; ++ct) {
        const int col = ct * 16 + l15;
#pragma unroll
        for (int r = 0; r < 4; ++r) {
            const int rr = blockIdx.x * 64 + wave * 16 + quad * 4 + r;
            yo[(size_t)rr * 48 + col] = acc[ct][r];
        }
    }
}

// ---------------- generic MFMA conv: f32 source + fused BN/ReLU (stages C, D, E) ----------------
template<int K, int CIN, int CINP, int COUT, int COUTP, int KG, int CG>
__global__ __launch_bounds__(256) void mconvF(
    const float* __restrict__ x,      // [Nin, CIN] f32 raw conv output
    const float* __restrict__ ss,     // [2*CIN] scale, shift
    const int*   __restrict__ neigh,  // [M, K]
    const ush_t* __restrict__ Wb,     // [K*CINP/32][COUTP][32]
    float*       __restrict__ yout, size_t ystride)
{
    constexpr int CPT  = CINP / 32;
    constexpr int NCHT = K * CPT;
    constexpr int NCH  = NCHT / KG;
    constexpr int NCT  = (COUTP / 16) / CG;
    const int tid = threadIdx.x;
    const int lane = tid & 63, wave = tid >> 6;
    const int quad = lane >> 4, l15 = lane & 15;
    const int kg = blockIdx.y, cg = blockIdx.z;
    const int rowA = blockIdx.x * 64 + wave * 16 + l15;

    float sc[CPT][8], sh[CPT][8];
#pragma unroll
    for (int sub = 0; sub < CPT; ++sub) {
        const int c0 = sub * 32 + quad * 8;
        if (c0 < CIN) {
#pragma unroll
            for (int j = 0; j < 8; ++j) { sc[sub][j] = ss[c0 + j]; sh[sub][j] = ss[CIN + c0 + j]; }
        } else {
#pragma unroll
            for (int j = 0; j < 8; ++j) { sc[sub][j] = 0.f; sh[sub][j] = 0.f; }
        }
    }

    f32x4 acc[NCT] = {};
#pragma unroll
    for (int ci = 0; ci < NCH; ++ci) {
        const int ch  = kg * NCH + ci;
        const int t   = ch / CPT;
        const int sub = ch % CPT;
        const int idx = neigh[(size_t)rowA * K + t];
        const int c0  = sub * 32 + quad * 8;
        uint4 au = make_uint4(0, 0, 0, 0);
        if (c0 < CIN) {
            const float4 v0 = *(const float4*)(x + (size_t)idx * CIN + c0);
            const float4 v1 = *(const float4*)(x + (size_t)idx * CIN + c0 + 4);
            const float vv[8] = {v0.x, v0.y, v0.z, v0.w, v1.x, v1.y, v1.z, v1.w};
            unsigned int o4[4];
#pragma unroll
            for (int h = 0; h < 4; ++h) {
                const float a0 = fmaxf(vv[2 * h]     * sc[sub][2 * h]     + sh[sub][2 * h],     0.f);
                const float a1 = fmaxf(vv[2 * h + 1] * sc[sub][2 * h + 1] + sh[sub][2 * h + 1], 0.f);
                o4[h] = (unsigned)f2bf(a0) | ((unsigned)f2bf(a1) << 16);
            }
            au = make_uint4(o4[0], o4[1], o4[2], o4[3]);
        }
        const bf16x8 af = as_bf8(au);
#pragma unroll
        for (int ct = 0; ct < NCT; ++ct) {
            const int n = (cg * NCT + ct) * 16 + l15;
            const uint4 bu = *(const uint4*)(Wb + ((size_t)ch * COUTP + n) * 32 + quad * 8);
            acc[ct] = __builtin_amdgcn_mfma_f32_16x16x32_bf16(af, as_bf8(bu), acc[ct], 0, 0, 0);
        }
    }

    float* yo = yout + (size_t)kg * ystride;
#pragma unroll
    for (int ct = 0; ct < NCT; ++ct) {
        const int col = (cg * NCT + ct) * 16 + l15;
#pragma unroll
        for (int r = 0; r < 4; ++r) {
            const int rr = blockIdx.x * 64 + wave * 16 + quad * 4 + r;
            yo[(size_t)rr * COUT + col] = acc[ct][r];
        }
    }
}

// ---------------- stats v2: vectorized partial-sum + moments + fused finalize ----------------
template<int C, int P, int NB>
__global__ __launch_bounds__(256) void stats2(
    const float* __restrict__ part, size_t pstride,
    float* __restrict__ yfull, int total, int M,
    const float* __restrict__ gamma_, const float* __restrict__ beta_,
    float* __restrict__ bins, int* __restrict__ counter, float* __restrict__ ss_out)
{
    __shared__ float lsq[2 * C];
    __shared__ int lastflag;
    const int tid = threadIdx.x;
    if (tid < 2 * C) lsq[tid] = 0.f;
    __syncthreads();

    float s4[4] = {0, 0, 0, 0}, q4[4] = {0, 0, 0, 0};
    int i = (blockIdx.x * 256 + tid) * 4;
    const int c0 = i % C;
    const int stride = gridDim.x * 1024;
    for (; i < total; i += stride) {
        float4 v = *(const float4*)(part + i);
#pragma unroll
        for (int p = 1; p < P; ++p) {
            const float4 w = *(const float4*)(part + (size_t)p * pstride + i);
            v.x += w.x; v.y += w.y; v.z += w.z; v.w += w.w;
        }
        *(float4*)(yfull + i) = v;
        s4[0] += v.x; q4[0] += v.x * v.x;
        s4[1] += v.y; q4[1] += v.y * v.y;
        s4[2] += v.z; q4[2] += v.z * v.z;
        s4[3] += v.w; q4[3] += v.w * v.w;
    }
#pragma unroll
    for (int j = 0; j < 4; ++j) {
        atomicAdd(&lsq[c0 + j], s4[j]);
        atomicAdd(&lsq[C + c0 + j], q4[j]);
    }
    __syncthreads();
    if (tid < 2 * C) atomicAdd(&bins[(blockIdx.x % NB) * 2 * C + tid], lsq[tid]);
    if (tid == 0) {
        __threadfence();
        int p = __hip_atomic_fetch_add(counter, 1, __ATOMIC_ACQ_REL, __HIP_MEMORY_SCOPE_AGENT);
        lastflag = (p == (int)gridDim.x - 1) ? 1 : 0;
    }
    __syncthreads();
    if (lastflag && tid < C) {
        float S = 0.f, Q = 0.f;
        for (int b2 = 0; b2 < NB; ++b2) {
            S += __hip_atomic_load(&bins[b2 * 2 * C + tid],     __ATOMIC_RELAXED, __HIP_MEMORY_SCOPE_AGENT);
            Q += __hip_atomic_load(&bins[b2 * 2 * C + C + tid], __ATOMIC_RELAXED, __HIP_MEMORY_SCOPE_AGENT);
        }
        const float mu  = S / (float)M;
        const float var = fmaxf(Q / (float)M - mu * mu, 0.f);
        const float scale = gamma_[tid] / sqrtf(var + EPSBN);
        ss_out[tid]     = scale;
        ss_out[C + tid] = beta_[tid] - mu * scale;
    }
}

// ---------------- final write (f32 out) ----------------
__global__ void writeout_kernel(const float* __restrict__ y, const float* __restrict__ ss,
                                float* __restrict__ out, int total)
{
    int i = (blockIdx.x * blockDim.x + threadIdx.x) * 4;
    if (i >= total) return;
    float4 v = *(const float4*)(y + i);
    int c = i % 96;
    float4 o;
    o.x = fmaxf(v.x * ss[c + 0] + ss[96 + c + 0], 0.f);
    o.y = fmaxf(v.y * ss[c + 1] + ss[96 + c + 1], 0.f);
    o.z = fmaxf(v.z * ss[c + 2] + ss[96 + c + 2], 0.f);
    o.w = fmaxf(v.w * ss[c + 3] + ss[96 + c + 3], 0.f);
    *(float4*)(out + i) = o;
}

// ---------------- host ----------------
extern "C" void kernel_launch(void* const* d_in, const int* in_sizes, int n_in,
                              void* d_out, int out_size, void* d_ws, size_t ws_size,
                              hipStream_t stream)
{
    const float* data   = (const float*)d_in[0];
    const int*   neigh0 = (const int*)d_in[1];
    const int*   child0 = (const int*)d_in[2];
    const int*   neigh1 = (const int*)d_in[3];
    const int*   child1 = (const int*)d_in[4];
    const int*   neigh2 = (const int*)d_in[5];
    const float* w0  = (const float*)d_in[6];
    const float* g0  = (const float*)d_in[7];
    const float* b0  = (const float*)d_in[8];
    const float* wd0 = (const float*)d_in[9];
    const float* gd0 = (const float*)d_in[10];
    const float* bd0 = (const float*)d_in[11];
    const float* w1  = (const float*)d_in[12];
    const float* g1  = (const float*)d_in[13];
    const float* b1  = (const float*)d_in[14];
    const float* wd1 = (const float*)d_in[15];
    const float* gd1 = (const float*)d_in[16];
    const float* bd1 = (const float*)d_in[17];
    const float* wp  = (const float*)d_in[18];
    const float* gp  = (const float*)d_in[19];
    const float* bp  = (const float*)d_in[20];
    float* out = (float*)d_out;

    // header (float offsets)
    float* wsf = (float*)d_ws;
    int*   counters = (int*)d_ws;      // ints [0..8)
    float* binsA = wsf + 16;           // 16*48  -> 784
    float* binsB = wsf + 784;          // 16*96  -> 2320
    float* binsC = wsf + 2320;         //        -> 3856
    float* binsD = wsf + 3856;         // 16*192 -> 6928
    float* binsE = wsf + 6928;         //        -> 10000
    float* ss0 = wsf + 10000;
    float* ss1 = wsf + 10064;
    float* ss2 = wsf + 10176;
    float* ss3 = wsf + 10288;
    float* ss4 = wsf + 10480;          // ends 10672, pad 10752

    // arena
    float* YF   = wsf + 10752;                         // 1,572,864 f (y1/y2/y3/y4)
    float* PART = YF + (size_t)1572864;                // 3,538,944 f (partials)
    ush_t* Y0B  = (ush_t*)(PART + (size_t)3538944);    // 6,291,456 ush: y0 bf16 [N0,24]
    ush_t* XA   = Y0B + (size_t)6291456;               // 1,048,576 ush: packed input [N0,4]
    ush_t* WB   = XA + (size_t)1048576;                //   524,288 ush: prepped weights

    ush_t* wbA = WB;
    ush_t* wbB = WB + 4096;
    ush_t* wbC = WB + 16384;
    ush_t* wbD = WB + 99328;
    ush_t* wbE = WB + 148480;

    hipMemsetAsync(d_ws, 0, 10752 * sizeof(float), stream);

    const size_t s1 = (size_t)N1 * 48;
    const size_t s2 = (size_t)N2 * 96;

    prep_weights<<<dim3(972, 5), 256, 0, stream>>>(w0, wd0, w1, wd1, wp, wbA, wbB, wbC, wbD, wbE);
    prep_input<<<N0 / 256, 256, 0, stream>>>(data, XA, N0);

    // stage A: conv -> Y0B (bf16 pre-BN); small-grid stats -> ss0
    mconvA<<<N0 / 128, 256, 0, stream>>>(XA, neigh0, wbA, Y0B);
    statsA<<<384, 256, 0, stream>>>(Y0B, g0, b0, binsA, &counters[0], ss0);

    // stage B: fused activate(y0,ss0) gather -> partials(2); stats -> y1 (YF), ss1
    mconvB<<<dim3(N1 / 64, 2, 1), 256, 0, stream>>>(Y0B, ss0, child0, wbB, PART, s1);
    stats2<48, 2, 16><<<384, 256, 0, stream>>>(PART, s1, YF, N1 * 48, N1, gd0, bd0, binsB, &counters[1], ss1);

    // stage C: fused activate(y1,ss1) f32 gather -> partials(2); stats -> y2 (YF), ss2
    mconvF<27, 48, 64, 48, 48, 2, 1><<<dim3(N1 / 64, 2, 1), 256, 0, stream>>>(YF, ss1, neigh1, wbC, PART, s1);
    stats2<48, 2, 16><<<384, 256, 0, stream>>>(PART, s1, YF, N1 * 48, N1, g1, b1, binsC, &counters[2], ss2);

    // stage D: fused activate(y2,ss2) f32 gather -> partials(4); stats -> y3 (YF), ss3
    mconvF<8, 48, 64, 96, 96, 4, 3><<<dim3(N2 / 64, 4, 3), 256, 0, stream>>>(YF, ss2, child1, wbD, PART, s2);
    stats2<96, 4, 16><<<384, 256, 0, stream>>>(PART, s2, YF, N2 * 96, N2, gd1, bd1, binsD, &counters[3], ss3);

    // stage E: fused activate(y3,ss3) f32 gather -> partials(9); stats -> y4 (YF), ss4
    mconvF<27, 96, 96, 96, 96, 9, 2><<<dim3(N2 / 64, 9, 2), 256, 0, stream>>>(YF, ss3, neigh2, wbE, PART, s2);
    stats2<96, 9, 16><<<384, 256, 0, stream>>>(PART, s2, YF, N2 * 96, N2, gp, bp, binsE, &counters[4], ss4);

    // final normalize + relu -> out
    writeout_kernel<<<N2 * 96 / 4 / 256, 256, 0, stream>>>(YF, ss4, out, N2 * 96);

    (void)in_sizes; (void)n_in; (void)out_size; (void)ws_size;
}

// Round 12
// 260.053 us; speedup vs baseline: 1.2902x; 1.2902x over previous
//
#include <hip/hip_runtime.h>

// ---------------- problem constants ----------------
#define N0 262144
#define N1 32768
#define N2 4096
#define EPSBN 1e-5f

typedef unsigned short ush_t;
typedef __bf16 bf16x8 __attribute__((ext_vector_type(8)));
typedef float  f32x4  __attribute__((ext_vector_type(4)));

union ufcast { unsigned int u; float f; };
__device__ __forceinline__ float bflo(unsigned int p) { ufcast x; x.u = p << 16;          return x.f; }
__device__ __forceinline__ float bfhi(unsigned int p) { ufcast x; x.u = p & 0xffff0000u; return x.f; }
__device__ __forceinline__ ush_t f2bf(float f) {
    ufcast x; x.f = f;
    unsigned int u = x.u + 0x7fffu + ((x.u >> 16) & 1u);
    return (ush_t)(u >> 16);
}
__device__ __forceinline__ bf16x8 as_bf8(uint4 u) {
    union { uint4 u; bf16x8 b; } x; x.u = u; return x.b;
}

// ss computation from 16 bins (no fences: bins complete at kernel boundary).
// C = INPUT channel count of the normalized tensor. bins layout [16][2C].
// ssl must hold 2C floats; after call: ssl[0..C)=scale, ssl[C..2C)=shift.
template<int C>
__device__ __forceinline__ void compute_ss(const float* __restrict__ bins,
                                           const float* __restrict__ g, const float* __restrict__ b,
                                           float M, float* ssl)
{
    const int tid = threadIdx.x;
    if (tid < 2 * C) {
        float s = 0.f;
#pragma unroll
        for (int k = 0; k < 16; ++k) s += bins[k * 2 * C + tid];
        ssl[tid] = s;
    }
    __syncthreads();
    if (tid < C) {
        const float mu  = ssl[tid] / M;
        const float var = fmaxf(ssl[C + tid] / M - mu * mu, 0.f);
        const float sc  = g[tid] / sqrtf(var + EPSBN);
        const float sh  = b[tid] - mu * sc;
        ssl[tid] = sc; ssl[C + tid] = sh;
    }
    __syncthreads();
}

// ---------------- prep: all weights + input pack in one dispatch ----------------
template<int K, int CIN, int CINP_W, int COUT, int COUTP, int NCH>
__device__ __forceinline__ void prep_stage(const float* __restrict__ W, ush_t* __restrict__ Wb, int e) {
    const int k  = e & 31;
    const int n  = (e >> 5) % COUTP;
    const int ch = e / (32 * COUTP);
    const int kp = ch * 32 + k;
    const int t  = kp / CINP_W;
    const int c  = kp % CINP_W;
    float v = 0.f;
    if (t < K && c < CIN && n < COUT) v = W[((size_t)t * CIN + c) * COUT + n];
    Wb[e] = f2bf(v);
}

__global__ __launch_bounds__(256) void prep_all(
    const float* w0, const float* wd0, const float* w1, const float* wd1, const float* wp,
    const float* data,
    ush_t* wbA, ush_t* wbB, ush_t* wbC, ush_t* wbD, ush_t* wbE, ush_t* xa)
{
    const int e = blockIdx.x * 256 + threadIdx.x;
    switch (blockIdx.y) {
        case 0: if (e <   4096) prep_stage<27,  3,  4, 24, 32,  4>(w0,  wbA, e); break;
        case 1: if (e <  12288) prep_stage< 8, 24, 32, 48, 48,  8>(wd0, wbB, e); break;
        case 2: if (e <  82944) prep_stage<27, 48, 64, 48, 48, 54>(w1,  wbC, e); break;
        case 3: if (e <  49152) prep_stage< 8, 48, 64, 96, 96, 16>(wd1, wbD, e); break;
        case 4: if (e < 248832) prep_stage<27, 96, 96, 96, 96, 81>(wp,  wbE, e); break;
        case 5: if (e < N0) {
            const float* dp = data + (size_t)3 * e;
            unsigned int h0 = f2bf(dp[0]), h1 = f2bf(dp[1]), h2 = f2bf(dp[2]);
            uint2 v; v.x = h0 | (h1 << 16); v.y = h2;
            ((uint2*)xa)[e] = v;
        } break;
    }
}

// ---------------- stage A: MFMA conv + binned moment atomics (no fence) ----------------
__global__ __launch_bounds__(256) void mconvA_s(
    const ush_t* __restrict__ xa,     // [N0,4] bf16
    const int*   __restrict__ neigh,  // [N0,27]
    const ush_t* __restrict__ Wb,     // [4][32][32] bf16
    ush_t*       __restrict__ y,      // [N0,24] bf16 (pre-BN)
    float*       __restrict__ bins)   // [16][48]
{
    __shared__ int nl[64][29];
    __shared__ float lsq[48];
    const int tid = threadIdx.x;
    const int block0 = blockIdx.x * 64;

    for (int i = tid; i < 64 * 27; i += 256)
        nl[i / 27][i % 27] = neigh[(size_t)block0 * 27 + i];
    if (tid < 48) lsq[tid] = 0.f;
    __syncthreads();

    const int lane = tid & 63, wave = tid >> 6;
    const int quad = lane >> 4, l15 = lane & 15;
    const int lr = wave * 16 + l15;

    f32x4 acc[2] = {};
#pragma unroll
    for (int ch = 0; ch < 4; ++ch) {
        const int tA = ch * 8 + quad * 2;
        uint4 au = make_uint4(0, 0, 0, 0);
        if (ch < 3) {
            const uint2 lo = ((const uint2*)xa)[nl[lr][tA]];
            const uint2 hi = ((const uint2*)xa)[nl[lr][tA + 1]];
            au = make_uint4(lo.x, lo.y, hi.x, hi.y);
        } else {
            if (quad == 0) {
                const uint2 lo = ((const uint2*)xa)[nl[lr][24]];
                const uint2 hi = ((const uint2*)xa)[nl[lr][25]];
                au = make_uint4(lo.x, lo.y, hi.x, hi.y);
            } else if (quad == 1) {
                const uint2 lo = ((const uint2*)xa)[nl[lr][26]];
                au = make_uint4(lo.x, lo.y, 0, 0);
            }
        }
        const bf16x8 af = as_bf8(au);
#pragma unroll
        for (int ct = 0; ct < 2; ++ct) {
            const int n = ct * 16 + l15;
            const uint4 bu = *(const uint4*)(Wb + ((size_t)ch * 32 + n) * 32 + quad * 8);
            acc[ct] = __builtin_amdgcn_mfma_f32_16x16x32_bf16(af, as_bf8(bu), acc[ct], 0, 0, 0);
        }
    }

#pragma unroll
    for (int ct = 0; ct < 2; ++ct) {
        const int col = ct * 16 + l15;
        if (col < 24) {
            float s = 0.f, q = 0.f;
#pragma unroll
            for (int r = 0; r < 4; ++r) {
                const float v = acc[ct][r];
                const int rr = block0 + wave * 16 + quad * 4 + r;
                y[(size_t)rr * 24 + col] = f2bf(v);
                s += v; q += v * v;
            }
            atomicAdd(&lsq[col], s);
            atomicAdd(&lsq[24 + col], q);
        }
    }
    __syncthreads();
    if (tid < 48) atomicAdd(&bins[(blockIdx.x & 15) * 48 + tid], lsq[tid]);
}

// ---------------- stage B: ss0 in-kernel; gather y0 bf16 + fused BN/ReLU; full K; moments ----------------
__global__ __launch_bounds__(256) void mconvB_s(
    const ush_t* __restrict__ y0,     // [N0,24] bf16 pre-BN
    const float* __restrict__ bins0,  // [16][48]
    const float* __restrict__ g, const float* __restrict__ b,
    const int*   __restrict__ child,  // [N1,8]
    const ush_t* __restrict__ Wb,     // [8][48][32]
    float*       __restrict__ y1,     // [N1,48]
    float*       __restrict__ bins1)  // [16][96]
{
    __shared__ float ssl[48];
    __shared__ float lsq[96];
    const int tid = threadIdx.x;
    if (tid < 96) lsq[tid] = 0.f;
    compute_ss<24>(bins0, g, b, (float)N0, ssl);

    const int lane = tid & 63, wave = tid >> 6;
    const int quad = lane >> 4, l15 = lane & 15;
    const int rowA = blockIdx.x * 64 + wave * 16 + l15;
    const int c0 = quad * 8;

    float sc[8], sh[8];
    if (c0 < 24) {
#pragma unroll
        for (int j = 0; j < 8; ++j) { sc[j] = ssl[c0 + j]; sh[j] = ssl[24 + c0 + j]; }
    }

    f32x4 acc[3] = {};
#pragma unroll
    for (int ci = 0; ci < 8; ++ci) {
        const int idx = child[(size_t)rowA * 8 + ci];
        uint4 au = make_uint4(0, 0, 0, 0);
        if (c0 < 24) {
            const uint4 raw = *(const uint4*)(y0 + (size_t)idx * 24 + c0);
            const unsigned int w4[4] = {raw.x, raw.y, raw.z, raw.w};
            unsigned int o4[4];
#pragma unroll
            for (int h = 0; h < 4; ++h) {
                const float a0 = fmaxf(bflo(w4[h]) * sc[2 * h]     + sh[2 * h],     0.f);
                const float a1 = fmaxf(bfhi(w4[h]) * sc[2 * h + 1] + sh[2 * h + 1], 0.f);
                o4[h] = (unsigned)f2bf(a0) | ((unsigned)f2bf(a1) << 16);
            }
            au = make_uint4(o4[0], o4[1], o4[2], o4[3]);
        }
        const bf16x8 af = as_bf8(au);
#pragma unroll
        for (int ct = 0; ct < 3; ++ct) {
            const int n = ct * 16 + l15;
            const uint4 bu = *(const uint4*)(Wb + ((size_t)ci * 48 + n) * 32 + quad * 8);
            acc[ct] = __builtin_amdgcn_mfma_f32_16x16x32_bf16(af, as_bf8(bu), acc[ct], 0, 0, 0);
        }
    }

#pragma unroll
    for (int ct = 0; ct < 3; ++ct) {
        const int col = ct * 16 + l15;
        float s = 0.f, q = 0.f;
#pragma unroll
        for (int r = 0; r < 4; ++r) {
            const float v = acc[ct][r];
            const int rr = blockIdx.x * 64 + wave * 16 + quad * 4 + r;
            y1[(size_t)rr * 48 + col] = v;
            s += v; q += v * v;
        }
        atomicAdd(&lsq[col], s);
        atomicAdd(&lsq[48 + col], q);
    }
    __syncthreads();
    if (tid < 96) atomicAdd(&bins1[(blockIdx.x & 15) * 96 + tid], lsq[tid]);
}

// ---------------- actC: ss1 in-kernel; y1 f32 -> XB bf16 [N1,64] (pad zero) ----------------
__global__ __launch_bounds__(256) void actC_s(
    const float* __restrict__ y1, const float* __restrict__ bins1,
    const float* __restrict__ g, const float* __restrict__ b,
    ush_t* __restrict__ xb)
{
    __shared__ float ssl[96];
    compute_ss<48>(bins1, g, b, (float)N1, ssl);

    const int i = (blockIdx.x * 256 + threadIdx.x) * 4;   // over N1*64
    const int c = i % 64;
    ushort4 o;
    if (c >= 48) {
        o.x = o.y = o.z = o.w = 0;
    } else {
        const int r = i / 64;
        float4 v = *(const float4*)(y1 + (size_t)r * 48 + c);
        o.x = f2bf(fmaxf(v.x * ssl[c + 0] + ssl[48 + c + 0], 0.f));
        o.y = f2bf(fmaxf(v.y * ssl[c + 1] + ssl[48 + c + 1], 0.f));
        o.z = f2bf(fmaxf(v.z * ssl[c + 2] + ssl[48 + c + 2], 0.f));
        o.w = f2bf(fmaxf(v.w * ssl[c + 3] + ssl[48 + c + 3], 0.f));
    }
    *(ushort4*)(xb + i) = o;
}

// ---------------- stage C: bf16 gather (pre-activated), full K, moments ----------------
__global__ __launch_bounds__(256) void mconvC_s(
    const ush_t* __restrict__ xb,     // [N1,64] bf16
    const int*   __restrict__ neigh,  // [N1,27]
    const ush_t* __restrict__ Wb,     // [54][48][32]
    float*       __restrict__ y2,     // [N1,48]
    float*       __restrict__ bins2)  // [16][96]
{
    __shared__ float lsq[96];
    const int tid = threadIdx.x;
    if (tid < 96) lsq[tid] = 0.f;
    __syncthreads();

    const int lane = tid & 63, wave = tid >> 6;
    const int quad = lane >> 4, l15 = lane & 15;
    const int rowA = blockIdx.x * 64 + wave * 16 + l15;

    f32x4 acc[3] = {};
#pragma unroll 6
    for (int ch = 0; ch < 54; ++ch) {
        const int t = ch >> 1, sub = ch & 1;
        const int idx = neigh[(size_t)rowA * 27 + t];
        const uint4 au = *(const uint4*)(xb + (size_t)idx * 64 + sub * 32 + quad * 8);
        const bf16x8 af = as_bf8(au);
#pragma unroll
        for (int ct = 0; ct < 3; ++ct) {
            const int n = ct * 16 + l15;
            const uint4 bu = *(const uint4*)(Wb + ((size_t)ch * 48 + n) * 32 + quad * 8);
            acc[ct] = __builtin_amdgcn_mfma_f32_16x16x32_bf16(af, as_bf8(bu), acc[ct], 0, 0, 0);
        }
    }

#pragma unroll
    for (int ct = 0; ct < 3; ++ct) {
        const int col = ct * 16 + l15;
        float s = 0.f, q = 0.f;
#pragma unroll
        for (int r = 0; r < 4; ++r) {
            const float v = acc[ct][r];
            const int rr = blockIdx.x * 64 + wave * 16 + quad * 4 + r;
            y2[(size_t)rr * 48 + col] = v;
            s += v; q += v * v;
        }
        atomicAdd(&lsq[col], s);
        atomicAdd(&lsq[48 + col], q);
    }
    __syncthreads();
    if (tid < 96) atomicAdd(&bins2[(blockIdx.x & 15) * 96 + tid], lsq[tid]);
}

// ---------------- stage D: 16-row blocks, wave-split K, LDS-tile reduce, fused BN(48ch) gather ----------------
__global__ __launch_bounds__(256) void mconvD_s(
    const float* __restrict__ y2, const float* __restrict__ bins2,  // bins2: [16][96] (48-ch moments!)
    const float* __restrict__ g, const float* __restrict__ b,
    const int*   __restrict__ child,  // [N2,8]
    const ush_t* __restrict__ Wb,     // [16][96][32]
    float*       __restrict__ y3,     // [N2,96]
    float*       __restrict__ bins3)  // [16][192]
{
    __shared__ float ssl[96];         // FIX r11->r12: input has 48 channels, not 96
    __shared__ float tile[16 * 96];
    const int tid = threadIdx.x;
    for (int i = tid; i < 1536; i += 256) tile[i] = 0.f;
    compute_ss<48>(bins2, g, b, (float)N1, ssl);   // FIX: was compute_ss<96>

    const int lane = tid & 63, wave = tid >> 6;
    const int quad = lane >> 4, l15 = lane & 15;
    const int rowA = blockIdx.x * 16 + l15;

    f32x4 acc[6] = {};
#pragma unroll
    for (int u = 0; u < 4; ++u) {
        const int ci = wave * 4 + u;
        const int t = ci >> 1, sub = ci & 1;
        const int idx = child[(size_t)rowA * 8 + t];
        const int c0 = sub * 32 + quad * 8;
        uint4 au = make_uint4(0, 0, 0, 0);
        if (c0 < 48) {
            const float4 v0 = *(const float4*)(y2 + (size_t)idx * 48 + c0);
            const float4 v1 = *(const float4*)(y2 + (size_t)idx * 48 + c0 + 4);
            const float vv[8] = {v0.x, v0.y, v0.z, v0.w, v1.x, v1.y, v1.z, v1.w};
            unsigned int o4[4];
#pragma unroll
            for (int h = 0; h < 4; ++h) {
                const float a0 = fmaxf(vv[2 * h]     * ssl[c0 + 2 * h]     + ssl[48 + c0 + 2 * h],     0.f);
                const float a1 = fmaxf(vv[2 * h + 1] * ssl[c0 + 2 * h + 1] + ssl[48 + c0 + 2 * h + 1], 0.f);
                o4[h] = (unsigned)f2bf(a0) | ((unsigned)f2bf(a1) << 16);
            }
            au = make_uint4(o4[0], o4[1], o4[2], o4[3]);
        }
        const bf16x8 af = as_bf8(au);
#pragma unroll
        for (int ct = 0; ct < 6; ++ct) {
            const int n = ct * 16 + l15;
            const uint4 bu = *(const uint4*)(Wb + ((size_t)ci * 96 + n) * 32 + quad * 8);
            acc[ct] = __builtin_amdgcn_mfma_f32_16x16x32_bf16(af, as_bf8(bu), acc[ct], 0, 0, 0);
        }
    }

#pragma unroll
    for (int ct = 0; ct < 6; ++ct)
#pragma unroll
        for (int r = 0; r < 4; ++r)
            atomicAdd(&tile[(quad * 4 + r) * 96 + ct * 16 + l15], acc[ct][r]);
    __syncthreads();

    const size_t row0 = (size_t)blockIdx.x * 16;
    for (int i = tid; i < 1536; i += 256) y3[row0 * 96 + i] = tile[i];
    if (tid < 96) {
        float s = 0.f, q = 0.f;
#pragma unroll
        for (int r = 0; r < 16; ++r) { const float v = tile[r * 96 + tid]; s += v; q += v * v; }
        atomicAdd(&bins3[(blockIdx.x & 15) * 192 + tid], s);
        atomicAdd(&bins3[(blockIdx.x & 15) * 192 + 96 + tid], q);
    }
}

// ---------------- stage E: K=27, CIN=96; 16-row blocks, wave-split chunks (21/20/20/20) ----------------
__global__ __launch_bounds__(256) void mconvE_s(
    const float* __restrict__ y3, const float* __restrict__ bins3,  // bins3: [16][192] (96-ch moments)
    const float* __restrict__ g, const float* __restrict__ b,
    const int*   __restrict__ neigh,  // [N2,27]
    const ush_t* __restrict__ Wb,     // [81][96][32]
    float*       __restrict__ y4,     // [N2,96]
    float*       __restrict__ bins4)  // [16][192]
{
    __shared__ float ssl[192];
    __shared__ float tile[16 * 96];
    const int tid = threadIdx.x;
    for (int i = tid; i < 1536; i += 256) tile[i] = 0.f;
    compute_ss<96>(bins3, g, b, (float)N2, ssl);

    const int lane = tid & 63, wave = tid >> 6;
    const int quad = lane >> 4, l15 = lane & 15;
    const int rowA = blockIdx.x * 16 + l15;

    const int ci0 = (wave == 0) ? 0 : 21 + (wave - 1) * 20;
    const int cnt = (wave == 0) ? 21 : 20;

    f32x4 acc[6] = {};
    for (int u = 0; u < cnt; ++u) {
        const int ci = ci0 + u;
        const int t = ci / 3, sub = ci % 3;
        const int idx = neigh[(size_t)rowA * 27 + t];
        const int c0 = sub * 32 + quad * 8;
        const float4 v0 = *(const float4*)(y3 + (size_t)idx * 96 + c0);
        const float4 v1 = *(const float4*)(y3 + (size_t)idx * 96 + c0 + 4);
        const float vv[8] = {v0.x, v0.y, v0.z, v0.w, v1.x, v1.y, v1.z, v1.w};
        unsigned int o4[4];
#pragma unroll
        for (int h = 0; h < 4; ++h) {
            const float a0 = fmaxf(vv[2 * h]     * ssl[c0 + 2 * h]     + ssl[96 + c0 + 2 * h],     0.f);
            const float a1 = fmaxf(vv[2 * h + 1] * ssl[c0 + 2 * h + 1] + ssl[96 + c0 + 2 * h + 1], 0.f);
            o4[h] = (unsigned)f2bf(a0) | ((unsigned)f2bf(a1) << 16);
        }
        const bf16x8 af = as_bf8(make_uint4(o4[0], o4[1], o4[2], o4[3]));
#pragma unroll
        for (int ct = 0; ct < 6; ++ct) {
            const int n = ct * 16 + l15;
            const uint4 bu = *(const uint4*)(Wb + ((size_t)ci * 96 + n) * 32 + quad * 8);
            acc[ct] = __builtin_amdgcn_mfma_f32_16x16x32_bf16(af, as_bf8(bu), acc[ct], 0, 0, 0);
        }
    }

#pragma unroll
    for (int ct = 0; ct < 6; ++ct)
#pragma unroll
        for (int r = 0; r < 4; ++r)
            atomicAdd(&tile[(quad * 4 + r) * 96 + ct * 16 + l15], acc[ct][r]);
    __syncthreads();

    const size_t row0 = (size_t)blockIdx.x * 16;
    for (int i = tid; i < 1536; i += 256) y4[row0 * 96 + i] = tile[i];
    if (tid < 96) {
        float s = 0.f, q = 0.f;
#pragma unroll
        for (int r = 0; r < 16; ++r) { const float v = tile[r * 96 + tid]; s += v; q += v * v; }
        atomicAdd(&bins4[(blockIdx.x & 15) * 192 + tid], s);
        atomicAdd(&bins4[(blockIdx.x & 15) * 192 + 96 + tid], q);
    }
}

// ---------------- final write: ss4 in-kernel ----------------
__global__ __launch_bounds__(256) void writeout_s(
    const float* __restrict__ y4, const float* __restrict__ bins4,
    const float* __restrict__ g, const float* __restrict__ b,
    float* __restrict__ out)
{
    __shared__ float ssl[192];
    compute_ss<96>(bins4, g, b, (float)N2, ssl);

    const int i = (blockIdx.x * 256 + threadIdx.x) * 4;   // over N2*96
    const int c = i % 96;
    float4 v = *(const float4*)(y4 + i);
    float4 o;
    o.x = fmaxf(v.x * ssl[c + 0] + ssl[96 + c + 0], 0.f);
    o.y = fmaxf(v.y * ssl[c + 1] + ssl[96 + c + 1], 0.f);
    o.z = fmaxf(v.z * ssl[c + 2] + ssl[96 + c + 2], 0.f);
    o.w = fmaxf(v.w * ssl[c + 3] + ssl[96 + c + 3], 0.f);
    *(float4*)(out + i) = o;
}

// ---------------- host ----------------
extern "C" void kernel_launch(void* const* d_in, const int* in_sizes, int n_in,
                              void* d_out, int out_size, void* d_ws, size_t ws_size,
                              hipStream_t stream)
{
    const float* data   = (const float*)d_in[0];
    const int*   neigh0 = (const int*)d_in[1];
    const int*   child0 = (const int*)d_in[2];
    const int*   neigh1 = (const int*)d_in[3];
    const int*   child1 = (const int*)d_in[4];
    const int*   neigh2 = (const int*)d_in[5];
    const float* w0  = (const float*)d_in[6];
    const float* g0  = (const float*)d_in[7];
    const float* b0  = (const float*)d_in[8];
    const float* wd0 = (const float*)d_in[9];
    const float* gd0 = (const float*)d_in[10];
    const float* bd0 = (const float*)d_in[11];
    const float* w1  = (const float*)d_in[12];
    const float* g1  = (const float*)d_in[13];
    const float* b1  = (const float*)d_in[14];
    const float* wd1 = (const float*)d_in[15];
    const float* gd1 = (const float*)d_in[16];
    const float* bd1 = (const float*)d_in[17];
    const float* wp  = (const float*)d_in[18];
    const float* gp  = (const float*)d_in[19];
    const float* bp  = (const float*)d_in[20];
    float* out = (float*)d_out;

    // bins header (floats): zero 9984 floats
    float* wsf = (float*)d_ws;
    float* bins0 = wsf;            // 16*48  = 768
    float* bins1 = wsf + 768;      // 16*96  = 1536
    float* bins2 = wsf + 2304;     // 1536
    float* bins3 = wsf + 3840;     // 16*192 = 3072
    float* bins4 = wsf + 6912;     // 3072 -> 9984, pad to 10240

    // arena
    float* Y1  = wsf + 10240;                        // N1*48 = 1,572,864
    float* Y2  = Y1 + (size_t)1572864;               // 1,572,864
    float* Y3  = Y2 + (size_t)1572864;               // N2*96 = 393,216
    float* Y4  = Y3 + (size_t)393216;                // 393,216
    ush_t* Y0B = (ush_t*)(Y4 + (size_t)393216);      // 6,291,456 ush
    ush_t* XB  = Y0B + (size_t)6291456;              // 2,097,152 ush
    ush_t* XA  = XB + (size_t)2097152;               // 1,048,576 ush
    ush_t* WB  = XA + (size_t)1048576;               //   524,288 ush

    ush_t* wbA = WB;
    ush_t* wbB = WB + 4096;
    ush_t* wbC = WB + 16384;
    ush_t* wbD = WB + 99328;
    ush_t* wbE = WB + 148480;

    hipMemsetAsync(d_ws, 0, 9984 * sizeof(float), stream);

    prep_all<<<dim3(1024, 6), 256, 0, stream>>>(w0, wd0, w1, wd1, wp, data,
                                                wbA, wbB, wbC, wbD, wbE, XA);

    mconvA_s<<<N0 / 64, 256, 0, stream>>>(XA, neigh0, wbA, Y0B, bins0);
    mconvB_s<<<N1 / 64, 256, 0, stream>>>(Y0B, bins0, g0, b0, child0, wbB, Y1, bins1);
    actC_s  <<<N1 * 64 / 4 / 256, 256, 0, stream>>>(Y1, bins1, gd0, bd0, XB);
    mconvC_s<<<N1 / 64, 256, 0, stream>>>(XB, neigh1, wbC, Y2, bins2);
    mconvD_s<<<N2 / 16, 256, 0, stream>>>(Y2, bins2, g1, b1, child1, wbD, Y3, bins3);
    mconvE_s<<<N2 / 16, 256, 0, stream>>>(Y3, bins3, gd1, bd1, neigh2, wbE, Y4, bins4);
    writeout_s<<<N2 * 96 / 4 / 256, 256, 0, stream>>>(Y4, bins4, gp, bp, out);

    (void)in_sizes; (void)n_in; (void)out_size; (void)ws_size;
}

// Round 13
// 253.961 us; speedup vs baseline: 1.3211x; 1.0240x over previous
//
#include <hip/hip_runtime.h>

// ---------------- problem constants ----------------
#define N0 262144
#define N1 32768
#define N2 4096
#define EPSBN 1e-5f

typedef unsigned short ush_t;
typedef __bf16 bf16x8 __attribute__((ext_vector_type(8)));
typedef float  f32x4  __attribute__((ext_vector_type(4)));

union ufcast { unsigned int u; float f; };
__device__ __forceinline__ float bflo(unsigned int p) { ufcast x; x.u = p << 16;          return x.f; }
__device__ __forceinline__ float bfhi(unsigned int p) { ufcast x; x.u = p & 0xffff0000u; return x.f; }
__device__ __forceinline__ ush_t f2bf(float f) {
    ufcast x; x.f = f;
    unsigned int u = x.u + 0x7fffu + ((x.u >> 16) & 1u);
    return (ush_t)(u >> 16);
}
__device__ __forceinline__ bf16x8 as_bf8(uint4 u) {
    union { uint4 u; bf16x8 b; } x; x.u = u; return x.b;
}

// ss computation from 16 bins (no fences: bins complete at kernel boundary).
// C = channel count of the normalized tensor. bins layout [16][2C].
template<int C>
__device__ __forceinline__ void compute_ss(const float* __restrict__ bins,
                                           const float* __restrict__ g, const float* __restrict__ b,
                                           float M, float* ssl)
{
    const int tid = threadIdx.x;
    if (tid < 2 * C) {
        float s = 0.f;
#pragma unroll
        for (int k = 0; k < 16; ++k) s += bins[k * 2 * C + tid];
        ssl[tid] = s;
    }
    __syncthreads();
    if (tid < C) {
        const float mu  = ssl[tid] / M;
        const float var = fmaxf(ssl[C + tid] / M - mu * mu, 0.f);
        const float sc  = g[tid] / sqrtf(var + EPSBN);
        const float sh  = b[tid] - mu * sc;
        ssl[tid] = sc; ssl[C + tid] = sh;
    }
    __syncthreads();
}

// ---------------- prep: all weights + input pack in one dispatch ----------------
// Wb[ch][n][k]: global K index g = ch*32+k; t = g / CINP_W; c = g % CINP_W; zero when t>=K | c>=CIN | n>=COUT
template<int K, int CIN, int CINP_W, int COUT, int COUTP, int NCH>
__device__ __forceinline__ void prep_stage(const float* __restrict__ W, ush_t* __restrict__ Wb, int e) {
    const int k  = e & 31;
    const int n  = (e >> 5) % COUTP;
    const int ch = e / (32 * COUTP);
    const int kp = ch * 32 + k;
    const int t  = kp / CINP_W;
    const int c  = kp % CINP_W;
    float v = 0.f;
    if (t < K && c < CIN && n < COUT) v = W[((size_t)t * CIN + c) * COUT + n];
    Wb[e] = f2bf(v);
}

__global__ __launch_bounds__(256) void prep_all(
    const float* w0, const float* wd0, const float* w1, const float* wd1, const float* wp,
    const float* data,
    ush_t* wbA, ush_t* wbB, ush_t* wbC, ush_t* wbD, ush_t* wbE, ush_t* xa)
{
    const int e = blockIdx.x * 256 + threadIdx.x;
    switch (blockIdx.y) {
        case 0: if (e <   4096) prep_stage<27,  3,  4, 24, 32,  4>(w0,  wbA, e); break;
        case 1: if (e <  12288) prep_stage< 8, 24, 32, 48, 48,  8>(wd0, wbB, e); break;
        case 2: if (e <  64512) prep_stage<27, 48, 48, 48, 48, 42>(w1,  wbC, e); break;  // flattened-dense K
        case 3: if (e <  49152) prep_stage< 8, 48, 64, 96, 96, 16>(wd1, wbD, e); break;
        case 4: if (e < 248832) prep_stage<27, 96, 96, 96, 96, 81>(wp,  wbE, e); break;
        case 5: if (e < N0) {
            const float* dp = data + (size_t)3 * e;
            unsigned int h0 = f2bf(dp[0]), h1 = f2bf(dp[1]), h2 = f2bf(dp[2]);
            uint2 v; v.x = h0 | (h1 << 16); v.y = h2;
            ((uint2*)xa)[e] = v;
        } break;
    }
}

// ---------------- stage A: MFMA conv + binned moment atomics (no fence) ----------------
__global__ __launch_bounds__(256) void mconvA_s(
    const ush_t* __restrict__ xa,     // [N0,4] bf16
    const int*   __restrict__ neigh,  // [N0,27]
    const ush_t* __restrict__ Wb,     // [4][32][32] bf16
    ush_t*       __restrict__ y,      // [N0,24] bf16 (pre-BN)
    float*       __restrict__ bins)   // [16][48]
{
    __shared__ int nl[64][29];
    __shared__ float lsq[48];
    const int tid = threadIdx.x;
    const int block0 = blockIdx.x * 64;

    for (int i = tid; i < 64 * 27; i += 256)
        nl[i / 27][i % 27] = neigh[(size_t)block0 * 27 + i];
    if (tid < 48) lsq[tid] = 0.f;
    __syncthreads();

    const int lane = tid & 63, wave = tid >> 6;
    const int quad = lane >> 4, l15 = lane & 15;
    const int lr = wave * 16 + l15;

    f32x4 acc[2] = {};
#pragma unroll
    for (int ch = 0; ch < 4; ++ch) {
        const int tA = ch * 8 + quad * 2;
        uint4 au = make_uint4(0, 0, 0, 0);
        if (ch < 3) {
            const uint2 lo = ((const uint2*)xa)[nl[lr][tA]];
            const uint2 hi = ((const uint2*)xa)[nl[lr][tA + 1]];
            au = make_uint4(lo.x, lo.y, hi.x, hi.y);
        } else {
            if (quad == 0) {
                const uint2 lo = ((const uint2*)xa)[nl[lr][24]];
                const uint2 hi = ((const uint2*)xa)[nl[lr][25]];
                au = make_uint4(lo.x, lo.y, hi.x, hi.y);
            } else if (quad == 1) {
                const uint2 lo = ((const uint2*)xa)[nl[lr][26]];
                au = make_uint4(lo.x, lo.y, 0, 0);
            }
        }
        const bf16x8 af = as_bf8(au);
#pragma unroll
        for (int ct = 0; ct < 2; ++ct) {
            const int n = ct * 16 + l15;
            const uint4 bu = *(const uint4*)(Wb + ((size_t)ch * 32 + n) * 32 + quad * 8);
            acc[ct] = __builtin_amdgcn_mfma_f32_16x16x32_bf16(af, as_bf8(bu), acc[ct], 0, 0, 0);
        }
    }

#pragma unroll
    for (int ct = 0; ct < 2; ++ct) {
        const int col = ct * 16 + l15;
        if (col < 24) {
            float s = 0.f, q = 0.f;
#pragma unroll
            for (int r = 0; r < 4; ++r) {
                const float v = acc[ct][r];
                const int rr = block0 + wave * 16 + quad * 4 + r;
                y[(size_t)rr * 24 + col] = f2bf(v);
                s += v; q += v * v;
            }
            atomicAdd(&lsq[col], s);
            atomicAdd(&lsq[24 + col], q);
        }
    }
    __syncthreads();
    if (tid < 48) atomicAdd(&bins[(blockIdx.x & 15) * 48 + tid], lsq[tid]);
}

// ---------------- stage B: ss0 in-kernel; gather y0 bf16 + fused BN/ReLU; bf16 pre-BN out ----------------
__global__ __launch_bounds__(256) void mconvB_s(
    const ush_t* __restrict__ y0,     // [N0,24] bf16 pre-BN
    const float* __restrict__ bins0,  // [16][48]
    const float* __restrict__ g, const float* __restrict__ b,
    const int*   __restrict__ child,  // [N1,8]
    const ush_t* __restrict__ Wb,     // [8][48][32]
    ush_t*       __restrict__ y1b,    // [N1,48] bf16 (pre-BN)
    float*       __restrict__ bins1)  // [16][96]
{
    __shared__ float ssl[48];
    __shared__ float lsq[96];
    const int tid = threadIdx.x;
    if (tid < 96) lsq[tid] = 0.f;
    compute_ss<24>(bins0, g, b, (float)N0, ssl);

    const int lane = tid & 63, wave = tid >> 6;
    const int quad = lane >> 4, l15 = lane & 15;
    const int rowA = blockIdx.x * 64 + wave * 16 + l15;
    const int c0 = quad * 8;

    float sc[8], sh[8];
    if (c0 < 24) {
#pragma unroll
        for (int j = 0; j < 8; ++j) { sc[j] = ssl[c0 + j]; sh[j] = ssl[24 + c0 + j]; }
    }

    f32x4 acc[3] = {};
#pragma unroll
    for (int ci = 0; ci < 8; ++ci) {
        const int idx = child[(size_t)rowA * 8 + ci];
        uint4 au = make_uint4(0, 0, 0, 0);
        if (c0 < 24) {
            const uint4 raw = *(const uint4*)(y0 + (size_t)idx * 24 + c0);
            const unsigned int w4[4] = {raw.x, raw.y, raw.z, raw.w};
            unsigned int o4[4];
#pragma unroll
            for (int h = 0; h < 4; ++h) {
                const float a0 = fmaxf(bflo(w4[h]) * sc[2 * h]     + sh[2 * h],     0.f);
                const float a1 = fmaxf(bfhi(w4[h]) * sc[2 * h + 1] + sh[2 * h + 1], 0.f);
                o4[h] = (unsigned)f2bf(a0) | ((unsigned)f2bf(a1) << 16);
            }
            au = make_uint4(o4[0], o4[1], o4[2], o4[3]);
        }
        const bf16x8 af = as_bf8(au);
#pragma unroll
        for (int ct = 0; ct < 3; ++ct) {
            const int n = ct * 16 + l15;
            const uint4 bu = *(const uint4*)(Wb + ((size_t)ci * 48 + n) * 32 + quad * 8);
            acc[ct] = __builtin_amdgcn_mfma_f32_16x16x32_bf16(af, as_bf8(bu), acc[ct], 0, 0, 0);
        }
    }

#pragma unroll
    for (int ct = 0; ct < 3; ++ct) {
        const int col = ct * 16 + l15;
        float s = 0.f, q = 0.f;
#pragma unroll
        for (int r = 0; r < 4; ++r) {
            const float v = acc[ct][r];
            const int rr = blockIdx.x * 64 + wave * 16 + quad * 4 + r;
            y1b[(size_t)rr * 48 + col] = f2bf(v);
            s += v; q += v * v;
        }
        atomicAdd(&lsq[col], s);
        atomicAdd(&lsq[48 + col], q);
    }
    __syncthreads();
    if (tid < 96) atomicAdd(&bins1[(blockIdx.x & 15) * 96 + tid], lsq[tid]);
}

// ---------------- stage C: ss1 in-kernel; flattened-dense K (42 chunks); fused BN gather ----------------
__global__ __launch_bounds__(256) void mconvC_s(
    const ush_t* __restrict__ y1b,    // [N1,48] bf16 pre-BN
    const float* __restrict__ bins1,  // [16][96]
    const float* __restrict__ g, const float* __restrict__ b,
    const int*   __restrict__ neigh,  // [N1,27]
    const ush_t* __restrict__ Wb,     // [42][48][32] (K rows g>=1296 zero)
    float*       __restrict__ y2,     // [N1,48]
    float*       __restrict__ bins2)  // [16][96]
{
    __shared__ float ssl[96];
    __shared__ float lsq[96];
    const int tid = threadIdx.x;
    if (tid < 96) lsq[tid] = 0.f;
    compute_ss<48>(bins1, g, b, (float)N1, ssl);

    const int lane = tid & 63, wave = tid >> 6;
    const int quad = lane >> 4, l15 = lane & 15;
    const int rowA = blockIdx.x * 64 + wave * 16 + l15;

    // chunk ch = 3*cg + m3: global k base g0 = 96*cg + 32*m3 + 8*quad
    // tap t = 2*cg + tof[m3], channel offset coff = (32*m3 + 8*quad) % 48  (period 3, cg-independent)
    int coffs[3], tofs[3];
    float sc[3][8], sh[3][8];
#pragma unroll
    for (int m3 = 0; m3 < 3; ++m3) {
        const int gg = 32 * m3 + 8 * quad;
        coffs[m3] = gg % 48;
        tofs[m3]  = gg / 48;
#pragma unroll
        for (int j = 0; j < 8; ++j) { sc[m3][j] = ssl[coffs[m3] + j]; sh[m3][j] = ssl[48 + coffs[m3] + j]; }
    }

    f32x4 acc[3] = {};
    for (int cg = 0; cg < 14; ++cg) {
#pragma unroll
        for (int m3 = 0; m3 < 3; ++m3) {
            const int ch = 3 * cg + m3;
            int t = 2 * cg + tofs[m3];
            if (t > 26) t = 26;                       // padded K rows have zero weights
            const int idx = neigh[(size_t)rowA * 27 + t];
            const uint4 raw = *(const uint4*)(y1b + (size_t)idx * 48 + coffs[m3]);
            const unsigned int w4[4] = {raw.x, raw.y, raw.z, raw.w};
            unsigned int o4[4];
#pragma unroll
            for (int h = 0; h < 4; ++h) {
                const float a0 = fmaxf(bflo(w4[h]) * sc[m3][2 * h]     + sh[m3][2 * h],     0.f);
                const float a1 = fmaxf(bfhi(w4[h]) * sc[m3][2 * h + 1] + sh[m3][2 * h + 1], 0.f);
                o4[h] = (unsigned)f2bf(a0) | ((unsigned)f2bf(a1) << 16);
            }
            const bf16x8 af = as_bf8(make_uint4(o4[0], o4[1], o4[2], o4[3]));
#pragma unroll
            for (int ct = 0; ct < 3; ++ct) {
                const int n = ct * 16 + l15;
                const uint4 bu = *(const uint4*)(Wb + ((size_t)ch * 48 + n) * 32 + quad * 8);
                acc[ct] = __builtin_amdgcn_mfma_f32_16x16x32_bf16(af, as_bf8(bu), acc[ct], 0, 0, 0);
            }
        }
    }

#pragma unroll
    for (int ct = 0; ct < 3; ++ct) {
        const int col = ct * 16 + l15;
        float s = 0.f, q = 0.f;
#pragma unroll
        for (int r = 0; r < 4; ++r) {
            const float v = acc[ct][r];
            const int rr = blockIdx.x * 64 + wave * 16 + quad * 4 + r;
            y2[(size_t)rr * 48 + col] = v;
            s += v; q += v * v;
        }
        atomicAdd(&lsq[col], s);
        atomicAdd(&lsq[48 + col], q);
    }
    __syncthreads();
    if (tid < 96) atomicAdd(&bins2[(blockIdx.x & 15) * 96 + tid], lsq[tid]);
}

// ---------------- stage D: 16-row blocks, wave-split K, LDS-tile reduce, fused BN(48ch) gather ----------------
__global__ __launch_bounds__(256) void mconvD_s(
    const float* __restrict__ y2, const float* __restrict__ bins2,  // bins2: [16][96] (48-ch moments)
    const float* __restrict__ g, const float* __restrict__ b,
    const int*   __restrict__ child,  // [N2,8]
    const ush_t* __restrict__ Wb,     // [16][96][32]
    float*       __restrict__ y3,     // [N2,96]
    float*       __restrict__ bins3)  // [16][192]
{
    __shared__ float ssl[96];
    __shared__ float tile[16 * 96];
    const int tid = threadIdx.x;
    for (int i = tid; i < 1536; i += 256) tile[i] = 0.f;
    compute_ss<48>(bins2, g, b, (float)N1, ssl);

    const int lane = tid & 63, wave = tid >> 6;
    const int quad = lane >> 4, l15 = lane & 15;
    const int rowA = blockIdx.x * 16 + l15;

    f32x4 acc[6] = {};
#pragma unroll
    for (int u = 0; u < 4; ++u) {
        const int ci = wave * 4 + u;
        const int t = ci >> 1, sub = ci & 1;
        const int idx = child[(size_t)rowA * 8 + t];
        const int c0 = sub * 32 + quad * 8;
        uint4 au = make_uint4(0, 0, 0, 0);
        if (c0 < 48) {
            const float4 v0 = *(const float4*)(y2 + (size_t)idx * 48 + c0);
            const float4 v1 = *(const float4*)(y2 + (size_t)idx * 48 + c0 + 4);
            const float vv[8] = {v0.x, v0.y, v0.z, v0.w, v1.x, v1.y, v1.z, v1.w};
            unsigned int o4[4];
#pragma unroll
            for (int h = 0; h < 4; ++h) {
                const float a0 = fmaxf(vv[2 * h]     * ssl[c0 + 2 * h]     + ssl[48 + c0 + 2 * h],     0.f);
                const float a1 = fmaxf(vv[2 * h + 1] * ssl[c0 + 2 * h + 1] + ssl[48 + c0 + 2 * h + 1], 0.f);
                o4[h] = (unsigned)f2bf(a0) | ((unsigned)f2bf(a1) << 16);
            }
            au = make_uint4(o4[0], o4[1], o4[2], o4[3]);
        }
        const bf16x8 af = as_bf8(au);
#pragma unroll
        for (int ct = 0; ct < 6; ++ct) {
            const int n = ct * 16 + l15;
            const uint4 bu = *(const uint4*)(Wb + ((size_t)ci * 96 + n) * 32 + quad * 8);
            acc[ct] = __builtin_amdgcn_mfma_f32_16x16x32_bf16(af, as_bf8(bu), acc[ct], 0, 0, 0);
        }
    }

#pragma unroll
    for (int ct = 0; ct < 6; ++ct)
#pragma unroll
        for (int r = 0; r < 4; ++r)
            atomicAdd(&tile[(quad * 4 + r) * 96 + ct * 16 + l15], acc[ct][r]);
    __syncthreads();

    const size_t row0 = (size_t)blockIdx.x * 16;
    for (int i = tid; i < 1536; i += 256) y3[row0 * 96 + i] = tile[i];
    if (tid < 96) {
        float s = 0.f, q = 0.f;
#pragma unroll
        for (int r = 0; r < 16; ++r) { const float v = tile[r * 96 + tid]; s += v; q += v * v; }
        atomicAdd(&bins3[(blockIdx.x & 15) * 192 + tid], s);
        atomicAdd(&bins3[(blockIdx.x & 15) * 192 + 96 + tid], q);
    }
}

// ---------------- stage E: K=27, CIN=96; 16-row blocks, wave-split chunks (21/20/20/20) ----------------
__global__ __launch_bounds__(256) void mconvE_s(
    const float* __restrict__ y3, const float* __restrict__ bins3,  // bins3: [16][192] (96-ch moments)
    const float* __restrict__ g, const float* __restrict__ b,
    const int*   __restrict__ neigh,  // [N2,27]
    const ush_t* __restrict__ Wb,     // [81][96][32]
    float*       __restrict__ y4,     // [N2,96]
    float*       __restrict__ bins4)  // [16][192]
{
    __shared__ float ssl[192];
    __shared__ float tile[16 * 96];
    const int tid = threadIdx.x;
    for (int i = tid; i < 1536; i += 256) tile[i] = 0.f;
    compute_ss<96>(bins3, g, b, (float)N2, ssl);

    const int lane = tid & 63, wave = tid >> 6;
    const int quad = lane >> 4, l15 = lane & 15;
    const int rowA = blockIdx.x * 16 + l15;

    const int ci0 = (wave == 0) ? 0 : 21 + (wave - 1) * 20;
    const int cnt = (wave == 0) ? 21 : 20;

    f32x4 acc[6] = {};
    for (int u = 0; u < cnt; ++u) {
        const int ci = ci0 + u;
        const int t = ci / 3, sub = ci % 3;
        const int idx = neigh[(size_t)rowA * 27 + t];
        const int c0 = sub * 32 + quad * 8;
        const float4 v0 = *(const float4*)(y3 + (size_t)idx * 96 + c0);
        const float4 v1 = *(const float4*)(y3 + (size_t)idx * 96 + c0 + 4);
        const float vv[8] = {v0.x, v0.y, v0.z, v0.w, v1.x, v1.y, v1.z, v1.w};
        unsigned int o4[4];
#pragma unroll
        for (int h = 0; h < 4; ++h) {
            const float a0 = fmaxf(vv[2 * h]     * ssl[c0 + 2 * h]     + ssl[96 + c0 + 2 * h],     0.f);
            const float a1 = fmaxf(vv[2 * h + 1] * ssl[c0 + 2 * h + 1] + ssl[96 + c0 + 2 * h + 1], 0.f);
            o4[h] = (unsigned)f2bf(a0) | ((unsigned)f2bf(a1) << 16);
        }
        const bf16x8 af = as_bf8(make_uint4(o4[0], o4[1], o4[2], o4[3]));
#pragma unroll
        for (int ct = 0; ct < 6; ++ct) {
            const int n = ct * 16 + l15;
            const uint4 bu = *(const uint4*)(Wb + ((size_t)ci * 96 + n) * 32 + quad * 8);
            acc[ct] = __builtin_amdgcn_mfma_f32_16x16x32_bf16(af, as_bf8(bu), acc[ct], 0, 0, 0);
        }
    }

#pragma unroll
    for (int ct = 0; ct < 6; ++ct)
#pragma unroll
        for (int r = 0; r < 4; ++r)
            atomicAdd(&tile[(quad * 4 + r) * 96 + ct * 16 + l15], acc[ct][r]);
    __syncthreads();

    const size_t row0 = (size_t)blockIdx.x * 16;
    for (int i = tid; i < 1536; i += 256) y4[row0 * 96 + i] = tile[i];
    if (tid < 96) {
        float s = 0.f, q = 0.f;
#pragma unroll
        for (int r = 0; r < 16; ++r) { const float v = tile[r * 96 + tid]; s += v; q += v * v; }
        atomicAdd(&bins4[(blockIdx.x & 15) * 192 + tid], s);
        atomicAdd(&bins4[(blockIdx.x & 15) * 192 + 96 + tid], q);
    }
}

// ---------------- final write: ss4 in-kernel ----------------
__global__ __launch_bounds__(256) void writeout_s(
    const float* __restrict__ y4, const float* __restrict__ bins4,
    const float* __restrict__ g, const float* __restrict__ b,
    float* __restrict__ out)
{
    __shared__ float ssl[192];
    compute_ss<96>(bins4, g, b, (float)N2, ssl);

    const int i = (blockIdx.x * 256 + threadIdx.x) * 4;   // over N2*96
    const int c = i % 96;
    float4 v = *(const float4*)(y4 + i);
    float4 o;
    o.x = fmaxf(v.x * ssl[c + 0] + ssl[96 + c + 0], 0.f);
    o.y = fmaxf(v.y * ssl[c + 1] + ssl[96 + c + 1], 0.f);
    o.z = fmaxf(v.z * ssl[c + 2] + ssl[96 + c + 2], 0.f);
    o.w = fmaxf(v.w * ssl[c + 3] + ssl[96 + c + 3], 0.f);
    *(float4*)(out + i) = o;
}

// ---------------- host ----------------
extern "C" void kernel_launch(void* const* d_in, const int* in_sizes, int n_in,
                              void* d_out, int out_size, void* d_ws, size_t ws_size,
                              hipStream_t stream)
{
    const float* data   = (const float*)d_in[0];
    const int*   neigh0 = (const int*)d_in[1];
    const int*   child0 = (const int*)d_in[2];
    const int*   neigh1 = (const int*)d_in[3];
    const int*   child1 = (const int*)d_in[4];
    const int*   neigh2 = (const int*)d_in[5];
    const float* w0  = (const float*)d_in[6];
    const float* g0  = (const float*)d_in[7];
    const float* b0  = (const float*)d_in[8];
    const float* wd0 = (const float*)d_in[9];
    const float* gd0 = (const float*)d_in[10];
    const float* bd0 = (const float*)d_in[11];
    const float* w1  = (const float*)d_in[12];
    const float* g1  = (const float*)d_in[13];
    const float* b1  = (const float*)d_in[14];
    const float* wd1 = (const float*)d_in[15];
    const float* gd1 = (const float*)d_in[16];
    const float* bd1 = (const float*)d_in[17];
    const float* wp  = (const float*)d_in[18];
    const float* gp  = (const float*)d_in[19];
    const float* bp  = (const float*)d_in[20];
    float* out = (float*)d_out;

    // bins header (floats): zero 9984 floats
    float* wsf = (float*)d_ws;
    float* bins0 = wsf;            // 16*48  = 768
    float* bins1 = wsf + 768;      // 16*96  = 1536
    float* bins2 = wsf + 2304;     // 1536
    float* bins3 = wsf + 3840;     // 16*192 = 3072
    float* bins4 = wsf + 6912;     // 3072 -> 9984, pad to 10240

    // arena
    float* Y2  = wsf + 10240;                        // N1*48 = 1,572,864 f
    float* Y3  = Y2 + (size_t)1572864;               // N2*96 =   393,216 f
    float* Y4  = Y3 + (size_t)393216;                //   393,216 f
    ush_t* Y0B = (ush_t*)(Y4 + (size_t)393216);      // 6,291,456 ush: y0 bf16 [N0,24]
    ush_t* Y1B = Y0B + (size_t)6291456;              // 1,572,864 ush: y1 bf16 [N1,48]
    ush_t* XA  = Y1B + (size_t)1572864;              // 1,048,576 ush: packed input [N0,4]
    ush_t* WB  = XA + (size_t)1048576;               //   524,288 ush: prepped weights

    ush_t* wbA = WB;                 //   4,096
    ush_t* wbB = WB + 4096;          //  12,288
    ush_t* wbC = WB + 16384;         //  64,512 (flattened 42 chunks)
    ush_t* wbD = WB + 80896;         //  49,152
    ush_t* wbE = WB + 130048;        // 248,832 -> end 378,880

    hipMemsetAsync(d_ws, 0, 9984 * sizeof(float), stream);

    prep_all<<<dim3(1024, 6), 256, 0, stream>>>(w0, wd0, w1, wd1, wp, data,
                                                wbA, wbB, wbC, wbD, wbE, XA);

    mconvA_s<<<N0 / 64, 256, 0, stream>>>(XA, neigh0, wbA, Y0B, bins0);
    mconvB_s<<<N1 / 64, 256, 0, stream>>>(Y0B, bins0, g0, b0, child0, wbB, Y1B, bins1);
    mconvC_s<<<N1 / 64, 256, 0, stream>>>(Y1B, bins1, gd0, bd0, neigh1, wbC, Y2, bins2);
    mconvD_s<<<N2 / 16, 256, 0, stream>>>(Y2, bins2, g1, b1, child1, wbD, Y3, bins3);
    mconvE_s<<<N2 / 16, 256, 0, stream>>>(Y3, bins3, gd1, bd1, neigh2, wbE, Y4, bins4);
    writeout_s<<<N2 * 96 / 4 / 256, 256, 0, stream>>>(Y4, bins4, gp, bp, out);

    (void)in_sizes; (void)n_in; (void)out_size; (void)ws_size;
}